// Round 15
// baseline (2183.071 us; speedup 1.0000x reference)
//
#include <hip/hip_runtime.h>
#include <cstddef>

#define MDIM 512
#define DDIM 1024
#define BDIM 4096
#define NLAYERS 16

constexpr int BK = 32;

typedef float f32x2 __attribute__((ext_vector_type(2)));

__device__ __forceinline__ float softf(float v, float t) {
  // relu(v-t) - relu(-v-t) == copysign(max(|v|-t,0), v)
  return copysignf(fmaxf(fabsf(v) - t, 0.0f), v);
}

// ---------------------------------------------------------------------------
// C = P(rows x K, row-major) @ B(K x 4096, row-major), fused epilogue.
// Bit-exact accumulation: per output element one fma chain, k ascending
// (BK chunks ascending, kk ascending) — identical per-element chain to
// rounds 1/5/13/14 (absmax 0.2304688). v_pk_fma_f32 = two independent IEEE
// fmas; packing adjacent columns changes no per-element chain.
// Structure = round-14 with ONE change: BK 16 -> 32 halves the per-chunk
// vmcnt(0)+barrier drains (the remaining non-LDS overhead; LDS return path
// is the identified roofline at ~1.5-2.0 B/fma).
// MODE 0: layer-0 A-kernel; MODE 1: scan A-kernel; MODE 2: B-kernel (soft-Z)
// ---------------------------------------------------------------------------
template <int MODE, int K, int BN>
__global__ __launch_bounds__(256) void gemm_f32(
    const float* __restrict__ P, const float* __restrict__ Bm,
    const float* __restrict__ xg, const float* __restrict__ Ep,
    const float* __restrict__ Lp, const float* __restrict__ Zp,
    const float* __restrict__ beta1, const float* __restrict__ beta2,
    const float* __restrict__ beta3, const float* __restrict__ ss2,
    const float* __restrict__ apar, const float* __restrict__ apar1, int k,
    float* __restrict__ O0, float* __restrict__ O1, float* __restrict__ O2) {
  constexpr int NG = BN / 64;  // column groups of 4 (1 or 2)
  __shared__ __align__(16) float As[2][BK][68];  // padded
  __shared__ __align__(16) float Bs[2][BK][BN];

  const int tid = threadIdx.x;
  const int tn = tid & 15, tm = tid >> 4;  // micro-tile coords
  const int m0 = blockIdx.x * 64, n0 = blockIdx.y * BN;

  f32x2 acc[4][NG][2];  // [row][col-group][pair]
#pragma unroll
  for (int r = 0; r < 4; ++r)
#pragma unroll
    for (int g = 0; g < NG; ++g)
#pragma unroll
      for (int p = 0; p < 2; ++p) acc[r][g][p] = (f32x2)(0.0f);

  // A staging map: thread -> (row ar, k-chunk akc of 4); two k-halves
  const int ar = tid >> 2, akc = tid & 3;
  const float* gA = P + (size_t)(m0 + ar) * K + akc * 4;
  // B staging map
  const int br = (NG == 1) ? (tid >> 4) : (tid >> 5);
  const int bc = (NG == 1) ? (tid & 15) : (tid & 31);
  const float* gB = Bm + (size_t)br * BDIM + n0 + bc * 4;

  float4 ra0, ra1, rb[4];
  auto gload = [&](int k0) {
    ra0 = *reinterpret_cast<const float4*>(gA + (size_t)k0);
    ra1 = *reinterpret_cast<const float4*>(gA + (size_t)k0 + 16);
    if (NG == 1) {
      rb[0] = *reinterpret_cast<const float4*>(gB + (size_t)k0 * BDIM);
      rb[1] = *reinterpret_cast<const float4*>(gB + (size_t)(k0 + 16) * BDIM);
    } else {
      rb[0] = *reinterpret_cast<const float4*>(gB + (size_t)k0 * BDIM);
      rb[1] = *reinterpret_cast<const float4*>(gB + (size_t)(k0 + 8) * BDIM);
      rb[2] = *reinterpret_cast<const float4*>(gB + (size_t)(k0 + 16) * BDIM);
      rb[3] = *reinterpret_cast<const float4*>(gB + (size_t)(k0 + 24) * BDIM);
    }
  };
  auto stagewr = [&](int bb) {
    As[bb][akc * 4 + 0][ar] = ra0.x;
    As[bb][akc * 4 + 1][ar] = ra0.y;
    As[bb][akc * 4 + 2][ar] = ra0.z;
    As[bb][akc * 4 + 3][ar] = ra0.w;
    As[bb][akc * 4 + 16][ar] = ra1.x;
    As[bb][akc * 4 + 17][ar] = ra1.y;
    As[bb][akc * 4 + 18][ar] = ra1.z;
    As[bb][akc * 4 + 19][ar] = ra1.w;
    if (NG == 1) {
      *reinterpret_cast<float4*>(&Bs[bb][br][bc * 4]) = rb[0];
      *reinterpret_cast<float4*>(&Bs[bb][br + 16][bc * 4]) = rb[1];
    } else {
      *reinterpret_cast<float4*>(&Bs[bb][br][bc * 4]) = rb[0];
      *reinterpret_cast<float4*>(&Bs[bb][br + 8][bc * 4]) = rb[1];
      *reinterpret_cast<float4*>(&Bs[bb][br + 16][bc * 4]) = rb[2];
      *reinterpret_cast<float4*>(&Bs[bb][br + 24][bc * 4]) = rb[3];
    }
  };
  auto comp = [&](int bb) {
#pragma unroll
    for (int kk = 0; kk < BK; ++kk) {
      const float4 a4 = *reinterpret_cast<const float4*>(&As[bb][kk][tm * 4]);
      const float a[4] = {a4.x, a4.y, a4.z, a4.w};
      f32x2 bv[NG][2];
#pragma unroll
      for (int g = 0; g < NG; ++g) {
        bv[g][0] =
            *reinterpret_cast<const f32x2*>(&Bs[bb][kk][g * 64 + tn * 4]);
        bv[g][1] =
            *reinterpret_cast<const f32x2*>(&Bs[bb][kk][g * 64 + tn * 4 + 2]);
      }
#pragma unroll
      for (int r = 0; r < 4; ++r) {
        const f32x2 av = {a[r], a[r]};
#pragma unroll
        for (int g = 0; g < NG; ++g)
#pragma unroll
          for (int p = 0; p < 2; ++p)
            acc[r][g][p] =
                __builtin_elementwise_fma(av, bv[g][p], acc[r][g][p]);
      }
    }
  };

  constexpr int NS = K / BK;
  gload(0);
  stagewr(0);
  __syncthreads();
  int bb = 0;
#pragma unroll 1
  for (int t = 1; t < NS; ++t) {
    gload(t * BK);
    comp(bb);         // reads buffer bb
    stagewr(bb ^ 1);  // writes the other buffer — one barrier suffices
    __syncthreads();
    bb ^= 1;
  }
  comp(bb);

  // ---- epilogue (expressions identical to rounds 1/5/13/14) ----
  const float b1v = (MODE == 2) ? 0.f : beta1[k];
  float b2v = 0.f, b3v = 0.f, s2v = 0.f, a1v = 0.f, ap = 0.f;
  if (MODE == 1) {
    b2v = beta2[k - 1];
    b3v = beta3[k - 1];
    s2v = ss2[k - 1];
    a1v = apar1[k - 1];
  }
  if (MODE == 2) ap = apar[k];

#pragma unroll
  for (int r = 0; r < 4; ++r) {
    const int row = m0 + tm * 4 + r;
#pragma unroll
    for (int g = 0; g < NG; ++g) {
      const int col = n0 + g * 64 + tn * 4;
      const size_t off = (size_t)row * BDIM + col;
      float av[4];
#pragma unroll
      for (int j = 0; j < 4; ++j) av[j] = acc[r][g][j >> 1][j & 1];
      if (MODE == 2) {
        const float4 z4 = *reinterpret_cast<const float4*>(&Zp[off]);
        const float z[4] = {z4.x, z4.y, z4.z, z4.w};
        float4 o;
        float* op = reinterpret_cast<float*>(&o);
#pragma unroll
        for (int j = 0; j < 4; ++j) op[j] = softf(z[j] - av[j], ap);
        *reinterpret_cast<float4*>(&O0[off]) = o;
      } else {
        float ev[4], lv[4], xv[4];
        *reinterpret_cast<float4*>(&ev[0]) =
            *reinterpret_cast<const float4*>(&Ep[off]);
        *reinterpret_cast<float4*>(&lv[0]) =
            *reinterpret_cast<const float4*>(&Lp[off]);
        *reinterpret_cast<float4*>(&xv[0]) =
            *reinterpret_cast<const float4*>(&xg[off]);
        float vo[4], eo[4], lo_[4];
#pragma unroll
        for (int j = 0; j < 4; ++j) {
          const float az = av[j];
          if (MODE == 0) {
            const float t0 = az + ev[j] - xv[j];
            vo[j] = fmaf(b1v, t0, lv[j]);
            eo[j] = ev[j];
            lo_[j] = lv[j];
          } else {
            const float vv = fmaf(b2v, az + ev[j] - xv[j], lv[j]);
            const float en = softf(ev[j] - s2v * vv, a1v);
            const float tn_ = az + en - xv[j];
            const float ln = fmaf(b3v, tn_, lv[j]);
            eo[j] = en;
            lo_[j] = ln;
            vo[j] = fmaf(b1v, tn_, ln);
          }
        }
        *reinterpret_cast<float4*>(&O0[off]) =
            *reinterpret_cast<const float4*>(&vo[0]);
        *reinterpret_cast<float4*>(&O1[off]) =
            *reinterpret_cast<const float4*>(&eo[0]);
        *reinterpret_cast<float4*>(&O2[off]) =
            *reinterpret_cast<const float4*>(&lo_[0]);
      }
    }
  }
}

extern "C" void kernel_launch(void* const* d_in, const int* in_sizes, int n_in,
                              void* d_out, int out_size, void* d_ws,
                              size_t ws_size, hipStream_t stream) {
  (void)in_sizes;
  (void)n_in;
  (void)out_size;
  (void)ws_size;
  const float* x = (const float*)d_in[0];
  const float* A = (const float*)d_in[1];
  const float* W = (const float*)d_in[2];
  const float* Z0 = (const float*)d_in[3];
  const float* E0 = (const float*)d_in[4];
  const float* L0 = (const float*)d_in[5];
  const float* beta1 = (const float*)d_in[6];
  const float* beta2 = (const float*)d_in[7];
  const float* beta3 = (const float*)d_in[8];
  const float* ss2 = (const float*)d_in[9];
  const float* apar = (const float*)d_in[10];
  const float* apar1 = (const float*)d_in[11];

  constexpr size_t DB = (size_t)DDIM * BDIM;
  constexpr size_t MB = (size_t)MDIM * BDIM;
  float* Zall = (float*)d_out;
  float* Eall = Zall + (size_t)NLAYERS * DB;
  float* Lall = Eall + (size_t)NLAYERS * MB;
  float* Var = (float*)d_ws;  // MDIM*BDIM floats = 8 MiB

  const dim3 blk(256);
  const dim3 gA(MDIM / 64, BDIM / 64);   // 8 x 64  = 512 blocks (BN=64)
  const dim3 gB(DDIM / 64, BDIM / 128);  // 16 x 32 = 512 blocks (BN=128)

  // layer 0
  gemm_f32<0, DDIM, 64><<<gA, blk, 0, stream>>>(
      A, Z0, x, E0, L0, nullptr, beta1, beta2, beta3, ss2, apar, apar1, 0, Var,
      Eall, Lall);
  gemm_f32<2, MDIM, 128><<<gB, blk, 0, stream>>>(
      W, Var, nullptr, nullptr, nullptr, Z0, beta1, beta2, beta3, ss2, apar,
      apar1, 0, Zall, nullptr, nullptr);
  // layers 1..15
  for (int k = 1; k < NLAYERS; ++k) {
    const float* Zp = Zall + (size_t)(k - 1) * DB;
    gemm_f32<1, DDIM, 64><<<gA, blk, 0, stream>>>(
        A, Zp, x, Eall + (size_t)(k - 1) * MB, Lall + (size_t)(k - 1) * MB,
        nullptr, beta1, beta2, beta3, ss2, apar, apar1, k,
        Var, Eall + (size_t)k * MB, Lall + (size_t)k * MB);
    gemm_f32<2, MDIM, 128><<<gB, blk, 0, stream>>>(
        W + (size_t)k * DDIM * MDIM, Var, nullptr, nullptr, nullptr, Zp, beta1,
        beta2, beta3, ss2, apar, apar1, k, Zall + (size_t)k * DB, nullptr,
        nullptr);
  }
}

// Round 16
// 1980.129 us; speedup vs baseline: 1.1025x; 1.1025x over previous
//
#include <hip/hip_runtime.h>
#include <cstddef>

#define MDIM 512
#define DDIM 1024
#define BDIM 4096
#define NLAYERS 16

constexpr int BK = 16;

typedef float f32x2 __attribute__((ext_vector_type(2)));

__device__ __forceinline__ float softf(float v, float t) {
  // relu(v-t) - relu(-v-t) == copysign(max(|v|-t,0), v)
  return copysignf(fmaxf(fabsf(v) - t, 0.0f), v);
}

// ---------------------------------------------------------------------------
// C = P(rows x K, row-major) @ B(K x 4096, row-major), fused epilogue.
// Bit-exact accumulation: per output element one fma chain, k ascending
// (BK=16 chunks ascending, kk ascending) — identical per-element chain to
// rounds 1/5/13 (absmax 0.2304688). v_pk_fma_f32 = two INDEPENDENT IEEE
// fmas, so packing adjacent columns changes no per-element chain.
// This is the round-14 kernel (best measured: 1987 us), resubmitted as the
// kernel of record. Identified roofline: LDS return path at the
// coverage-capped microtile shapes (~1.75 B/fma avg -> ~1740 us pure-LDS at
// the 69 TB/s ceiling + staging/barrier overhead).
// MODE 0: layer-0 A-kernel; MODE 1: scan A-kernel; MODE 2: B-kernel (soft-Z)
// ---------------------------------------------------------------------------
template <int MODE, int K, int BN>
__global__ __launch_bounds__(256) void gemm_f32(
    const float* __restrict__ P, const float* __restrict__ Bm,
    const float* __restrict__ xg, const float* __restrict__ Ep,
    const float* __restrict__ Lp, const float* __restrict__ Zp,
    const float* __restrict__ beta1, const float* __restrict__ beta2,
    const float* __restrict__ beta3, const float* __restrict__ ss2,
    const float* __restrict__ apar, const float* __restrict__ apar1, int k,
    float* __restrict__ O0, float* __restrict__ O1, float* __restrict__ O2) {
  constexpr int NG = BN / 64;  // column groups of 4 (1 or 2)
  __shared__ __align__(16) float As[2][BK][68];  // padded
  __shared__ __align__(16) float Bs[2][BK][BN];

  const int tid = threadIdx.x;
  const int tn = tid & 15, tm = tid >> 4;  // micro-tile coords
  const int m0 = blockIdx.x * 64, n0 = blockIdx.y * BN;

  f32x2 acc[4][NG][2];  // [row][col-group][pair]: cols g*64+tn*4 + 2*p + h
#pragma unroll
  for (int r = 0; r < 4; ++r)
#pragma unroll
    for (int g = 0; g < NG; ++g)
#pragma unroll
      for (int p = 0; p < 2; ++p) acc[r][g][p] = (f32x2)(0.0f);

  // A staging map: thread -> (row ar, k-chunk akc of 4)
  const int ar = tid >> 2, akc = tid & 3;
  const float* gA = P + (size_t)(m0 + ar) * K + akc * 4;
  // B staging map
  const int br = (NG == 1) ? (tid >> 4) : (tid >> 5);
  const int bc = (NG == 1) ? (tid & 15) : (tid & 31);
  const float* gB = Bm + (size_t)br * BDIM + n0 + bc * 4;

  float4 ra, rb0, rb1;
  auto gload = [&](int k0) {
    ra = *reinterpret_cast<const float4*>(gA + (size_t)k0);
    rb0 = *reinterpret_cast<const float4*>(gB + (size_t)k0 * BDIM);
    if (NG == 2)
      rb1 = *reinterpret_cast<const float4*>(gB + (size_t)(k0 + 8) * BDIM);
  };
  auto stagewr = [&](int bb) {
    As[bb][akc * 4 + 0][ar] = ra.x;
    As[bb][akc * 4 + 1][ar] = ra.y;
    As[bb][akc * 4 + 2][ar] = ra.z;
    As[bb][akc * 4 + 3][ar] = ra.w;
    *reinterpret_cast<float4*>(&Bs[bb][br][bc * 4]) = rb0;
    if (NG == 2) *reinterpret_cast<float4*>(&Bs[bb][br + 8][bc * 4]) = rb1;
  };
  auto comp = [&](int bb) {
#pragma unroll
    for (int kk = 0; kk < BK; ++kk) {
      const float4 a4 = *reinterpret_cast<const float4*>(&As[bb][kk][tm * 4]);
      const float a[4] = {a4.x, a4.y, a4.z, a4.w};
      f32x2 bv[NG][2];
#pragma unroll
      for (int g = 0; g < NG; ++g) {
        bv[g][0] =
            *reinterpret_cast<const f32x2*>(&Bs[bb][kk][g * 64 + tn * 4]);
        bv[g][1] =
            *reinterpret_cast<const f32x2*>(&Bs[bb][kk][g * 64 + tn * 4 + 2]);
      }
#pragma unroll
      for (int r = 0; r < 4; ++r) {
        const f32x2 av = {a[r], a[r]};
#pragma unroll
        for (int g = 0; g < NG; ++g)
#pragma unroll
          for (int p = 0; p < 2; ++p)
            acc[r][g][p] = __builtin_elementwise_fma(av, bv[g][p], acc[r][g][p]);
      }
    }
  };

  constexpr int NS = K / BK;
  gload(0);
  stagewr(0);
  __syncthreads();
  int bb = 0;
#pragma unroll 1
  for (int t = 1; t < NS; ++t) {
    gload(t * BK);
    comp(bb);         // reads buffer bb
    stagewr(bb ^ 1);  // writes the other buffer — one barrier suffices
    __syncthreads();
    bb ^= 1;
  }
  comp(bb);

  // ---- epilogue (expressions identical to rounds 1/5/13) ----
  const float b1v = (MODE == 2) ? 0.f : beta1[k];
  float b2v = 0.f, b3v = 0.f, s2v = 0.f, a1v = 0.f, ap = 0.f;
  if (MODE == 1) {
    b2v = beta2[k - 1];
    b3v = beta3[k - 1];
    s2v = ss2[k - 1];
    a1v = apar1[k - 1];
  }
  if (MODE == 2) ap = apar[k];

#pragma unroll
  for (int r = 0; r < 4; ++r) {
    const int row = m0 + tm * 4 + r;
#pragma unroll
    for (int g = 0; g < NG; ++g) {
      const int col = n0 + g * 64 + tn * 4;
      const size_t off = (size_t)row * BDIM + col;
      float av[4];
#pragma unroll
      for (int j = 0; j < 4; ++j) av[j] = acc[r][g][j >> 1][j & 1];
      if (MODE == 2) {
        const float4 z4 = *reinterpret_cast<const float4*>(&Zp[off]);
        const float z[4] = {z4.x, z4.y, z4.z, z4.w};
        float4 o;
        float* op = reinterpret_cast<float*>(&o);
#pragma unroll
        for (int j = 0; j < 4; ++j) op[j] = softf(z[j] - av[j], ap);
        *reinterpret_cast<float4*>(&O0[off]) = o;
      } else {
        float ev[4], lv[4], xv[4];
        *reinterpret_cast<float4*>(&ev[0]) =
            *reinterpret_cast<const float4*>(&Ep[off]);
        *reinterpret_cast<float4*>(&lv[0]) =
            *reinterpret_cast<const float4*>(&Lp[off]);
        *reinterpret_cast<float4*>(&xv[0]) =
            *reinterpret_cast<const float4*>(&xg[off]);
        float vo[4], eo[4], lo_[4];
#pragma unroll
        for (int j = 0; j < 4; ++j) {
          const float az = av[j];
          if (MODE == 0) {
            const float t0 = az + ev[j] - xv[j];
            vo[j] = fmaf(b1v, t0, lv[j]);
            eo[j] = ev[j];
            lo_[j] = lv[j];
          } else {
            const float vv = fmaf(b2v, az + ev[j] - xv[j], lv[j]);
            const float en = softf(ev[j] - s2v * vv, a1v);
            const float tn_ = az + en - xv[j];
            const float ln = fmaf(b3v, tn_, lv[j]);
            eo[j] = en;
            lo_[j] = ln;
            vo[j] = fmaf(b1v, tn_, ln);
          }
        }
        *reinterpret_cast<float4*>(&O0[off]) =
            *reinterpret_cast<const float4*>(&vo[0]);
        *reinterpret_cast<float4*>(&O1[off]) =
            *reinterpret_cast<const float4*>(&eo[0]);
        *reinterpret_cast<float4*>(&O2[off]) =
            *reinterpret_cast<const float4*>(&lo_[0]);
      }
    }
  }
}

extern "C" void kernel_launch(void* const* d_in, const int* in_sizes, int n_in,
                              void* d_out, int out_size, void* d_ws,
                              size_t ws_size, hipStream_t stream) {
  (void)in_sizes;
  (void)n_in;
  (void)out_size;
  (void)ws_size;
  const float* x = (const float*)d_in[0];
  const float* A = (const float*)d_in[1];
  const float* W = (const float*)d_in[2];
  const float* Z0 = (const float*)d_in[3];
  const float* E0 = (const float*)d_in[4];
  const float* L0 = (const float*)d_in[5];
  const float* beta1 = (const float*)d_in[6];
  const float* beta2 = (const float*)d_in[7];
  const float* beta3 = (const float*)d_in[8];
  const float* ss2 = (const float*)d_in[9];
  const float* apar = (const float*)d_in[10];
  const float* apar1 = (const float*)d_in[11];

  constexpr size_t DB = (size_t)DDIM * BDIM;
  constexpr size_t MB = (size_t)MDIM * BDIM;
  float* Zall = (float*)d_out;
  float* Eall = Zall + (size_t)NLAYERS * DB;
  float* Lall = Eall + (size_t)NLAYERS * MB;
  float* Var = (float*)d_ws;  // MDIM*BDIM floats = 8 MiB

  const dim3 blk(256);
  const dim3 gA(MDIM / 64, BDIM / 64);   // 8 x 64  = 512 blocks (BN=64)
  const dim3 gB(DDIM / 64, BDIM / 128);  // 16 x 32 = 512 blocks (BN=128)

  // layer 0
  gemm_f32<0, DDIM, 64><<<gA, blk, 0, stream>>>(
      A, Z0, x, E0, L0, nullptr, beta1, beta2, beta3, ss2, apar, apar1, 0, Var,
      Eall, Lall);
  gemm_f32<2, MDIM, 128><<<gB, blk, 0, stream>>>(
      W, Var, nullptr, nullptr, nullptr, Z0, beta1, beta2, beta3, ss2, apar,
      apar1, 0, Zall, nullptr, nullptr);
  // layers 1..15
  for (int k = 1; k < NLAYERS; ++k) {
    const float* Zp = Zall + (size_t)(k - 1) * DB;
    gemm_f32<1, DDIM, 64><<<gA, blk, 0, stream>>>(
        A, Zp, x, Eall + (size_t)(k - 1) * MB, Lall + (size_t)(k - 1) * MB,
        nullptr, beta1, beta2, beta3, ss2, apar, apar1, k,
        Var, Eall + (size_t)k * MB, Lall + (size_t)k * MB);
    gemm_f32<2, MDIM, 128><<<gB, blk, 0, stream>>>(
        W + (size_t)k * DDIM * MDIM, Var, nullptr, nullptr, nullptr, Zp, beta1,
        beta2, beta3, ss2, apar, apar1, k, Zall + (size_t)k * DB, nullptr,
        nullptr);
  }
}